// Round 1
// baseline (5168.660 us; speedup 1.0000x reference)
//
#include <hip/hip_runtime.h>
#include <math.h>

#define HW   64
#define HW2  4096   // 64*64

// ---------------------------------------------------------------------------
// 3x3 conv + bias + relu, NCHW, H=W=64, pad=1.
// Block tile: 16x16 spatial x 32 output channels. 256 threads.
// Each thread: 1 h-row x 4 consecutive w x 8 co  (32 accumulators).
// K-loop over Cin in chunks of 8, staged in LDS.
// ---------------------------------------------------------------------------
__global__ __launch_bounds__(256) void conv3x3_relu_k(
    const float* __restrict__ in, const float* __restrict__ wt,
    const float* __restrict__ bias, float* __restrict__ out,
    int Cin, int co_off, int outC)
{
  __shared__ float sIn[8][18][20];   // 8 cin x 18 rows x 18 cols (padded to 20)
  __shared__ float sW[32][8][9];     // 32 co x 8 cin x 9 taps

  const int tid  = threadIdx.x;
  const int b    = blockIdx.z;
  const int co0  = blockIdx.y * 32;
  const int th   = blockIdx.x >> 2;
  const int tw   = blockIdx.x & 3;
  const int h0   = th * 16;
  const int w0   = tw * 16;
  const int lane = tid & 63;
  const int cog  = tid >> 6;     // wave id 0..3 -> co sub-group (uniform per wave)
  const int tx   = lane & 3;     // w quad: w = w0 + tx*4 + dw
  const int ty   = lane >> 2;    // h row 0..15

  float acc[8][4];
  #pragma unroll
  for (int u = 0; u < 8; ++u)
    acc[u][0] = acc[u][1] = acc[u][2] = acc[u][3] = 0.f;

  for (int c0 = 0; c0 < Cin; c0 += 8) {
    __syncthreads();
    // ---- stage input tile: 8 x 18 x 18 (halo of 1) ----
    for (int e = tid; e < 8 * 18 * 18; e += 256) {
      int c = e / 324; int rem = e - c * 324;
      int r = rem / 18; int x = rem - r * 18;
      int hh = h0 - 1 + r, ww = w0 - 1 + x;
      float v = 0.f;
      if (hh >= 0 && hh < 64 && ww >= 0 && ww < 64)
        v = in[(size_t)(b * Cin + c0 + c) * HW2 + hh * 64 + ww];
      sIn[c][r][x] = v;
    }
    // ---- stage weights: 32 co x 8 cin x 9 ----
    for (int e = tid; e < 32 * 72; e += 256) {
      int co = e / 72; int rem = e - co * 72;
      int c = rem / 9; int k = rem - c * 9;
      sW[co][c][k] = wt[(size_t)(co0 + co) * Cin * 9 + (size_t)(c0 + c) * 9 + k];
    }
    __syncthreads();

    // ---- compute ----
    #pragma unroll
    for (int c = 0; c < 8; ++c) {
      #pragma unroll
      for (int kh = 0; kh < 3; ++kh) {
        const float* rp = &sIn[c][ty + kh][tx * 4];
        float4 q  = *(const float4*)rp;        // cols +0..3  (16B aligned)
        float2 r2 = *(const float2*)(rp + 4);  // cols +4..5
        float f[6] = { q.x, q.y, q.z, q.w, r2.x, r2.y };
        #pragma unroll
        for (int kw = 0; kw < 3; ++kw) {
          #pragma unroll
          for (int u = 0; u < 8; ++u) {
            float wv = sW[cog * 8 + u][c][kh * 3 + kw];  // wave-uniform: broadcast
            acc[u][0] += f[kw + 0] * wv;
            acc[u][1] += f[kw + 1] * wv;
            acc[u][2] += f[kw + 2] * wv;
            acc[u][3] += f[kw + 3] * wv;
          }
        }
      }
    }
  }

  // ---- epilogue: bias + relu, float4 store ----
  #pragma unroll
  for (int u = 0; u < 8; ++u) {
    int co = co0 + cog * 8 + u;
    float bv = bias[co];
    float4 o;
    o.x = fmaxf(acc[u][0] + bv, 0.f);
    o.y = fmaxf(acc[u][1] + bv, 0.f);
    o.z = fmaxf(acc[u][2] + bv, 0.f);
    o.w = fmaxf(acc[u][3] + bv, 0.f);
    *(float4*)&out[(size_t)(b * outC + co_off + co) * HW2 +
                   (h0 + ty) * 64 + (w0 + tx * 4)] = o;
  }
}

// ---------------------------------------------------------------------------
// 1x1 conv (256 -> 81) + bias + relu + softmax over the 81 channels.
// One block per (b, h) row; 256 threads. Scores staged in LDS, softmax by
// 64 threads (one per w).
// ---------------------------------------------------------------------------
__global__ __launch_bounds__(256) void head_softmax_k(
    const float* __restrict__ x, const float* __restrict__ w3,
    const float* __restrict__ b3, float* __restrict__ kern)
{
  __shared__ float sS[81 * 64];
  const int bh = blockIdx.x;
  const int b  = bh >> 6;
  const int h  = bh & 63;
  const int tid = threadIdx.x;
  const int w  = tid & 63;
  const int cg = tid >> 6;

  const float* xp = x + (size_t)(b * 256) * HW2 + h * 64 + w;
  for (int cc = cg; cc < 81; cc += 4) {
    float a = b3[cc];
    const float* wp = w3 + cc * 256;
    #pragma unroll 4
    for (int c = 0; c < 256; ++c)
      a += xp[(size_t)c * HW2] * wp[c];
    sS[cc * 64 + w] = fmaxf(a, 0.f);
  }
  __syncthreads();
  if (tid < 64) {
    float m = -1e30f;
    for (int cc = 0; cc < 81; ++cc) m = fmaxf(m, sS[cc * 64 + tid]);
    float s = 0.f;
    for (int cc = 0; cc < 81; ++cc) {
      float e = __expf(sS[cc * 64 + tid] - m);
      sS[cc * 64 + tid] = e;
      s += e;
    }
    float r = 1.f / s;
    for (int cc = 0; cc < 81; ++cc)
      kern[(size_t)(b * 81 + cc) * HW2 + h * 64 + tid] = sS[cc * 64 + tid] * r;
  }
}

// ---------------------------------------------------------------------------
// Spatially-variant conv: out[b,c,h,w] = sum_ij featsPad[b,c,h+i,w+j]*kern[b,ij,h,w]
// Block: one (b, h) row x 16 channels. 256 threads: 16 w-quads x 16 channels.
// feats rows (9 x 72 halo) and kern row (81 x 64) staged in LDS; float4 math.
// ---------------------------------------------------------------------------
__global__ __launch_bounds__(256) void svc_k(
    const float* __restrict__ feats, const float* __restrict__ kern,
    float* __restrict__ out)
{
  __shared__ float sK[81 * 64];
  __shared__ float sF[16][9][72];
  const int b  = blockIdx.z;
  const int h  = blockIdx.y;
  const int cb = blockIdx.x * 16;
  const int tid = threadIdx.x;

  for (int e = tid; e < 81 * 64; e += 256) {
    int ij = e >> 6, w = e & 63;
    sK[e] = kern[(size_t)(b * 81 + ij) * HW2 + h * 64 + w];
  }
  for (int e = tid; e < 16 * 9 * 72; e += 256) {
    int c = e / 648; int rem = e - c * 648;
    int r = rem / 72; int x = rem - r * 72;
    int hh = h + r - 4, xx = x - 4;
    float v = 0.f;
    if (hh >= 0 && hh < 64 && xx >= 0 && xx < 64)
      v = feats[(size_t)(b * 1024 + cb + c) * HW2 + hh * 64 + xx];
    sF[c][r][x] = v;
  }
  __syncthreads();

  const int w4 = tid & 15;   // 4 consecutive w outputs
  const int c  = tid >> 4;   // channel within block
  float4 acc = make_float4(0.f, 0.f, 0.f, 0.f);
  #pragma unroll
  for (int i = 0; i < 9; ++i) {
    const float* fr = &sF[c][i][w4 * 4];
    float4 A  = *(const float4*)fr;
    float4 Bv = *(const float4*)(fr + 4);
    float4 Cv = *(const float4*)(fr + 8);
    float f[12] = { A.x, A.y, A.z, A.w, Bv.x, Bv.y, Bv.z, Bv.w,
                    Cv.x, Cv.y, Cv.z, Cv.w };
    #pragma unroll
    for (int j = 0; j < 9; ++j) {
      float4 kv = *(const float4*)&sK[(i * 9 + j) * 64 + w4 * 4];
      acc.x += f[j + 0] * kv.x;
      acc.y += f[j + 1] * kv.y;
      acc.z += f[j + 2] * kv.z;
      acc.w += f[j + 3] * kv.w;
    }
  }
  *(float4*)&out[(size_t)(b * 1024 + cb + c) * HW2 + h * 64 + w4 * 4] = acc;
}

// ---------------------------------------------------------------------------
extern "C" void kernel_launch(void* const* d_in, const int* in_sizes, int n_in,
                              void* d_out, int out_size, void* d_ws, size_t ws_size,
                              hipStream_t stream) {
  const float* cur  = (const float*)d_in[0];   // (4,1024,64,64)
  const float* keyl = (const float*)d_in[1];   // (4,1024,64,64)
  const float* keyh = (const float*)d_in[2];   // (4,1024,64,64)
  const float* w_r  = (const float*)d_in[3];   // (256,1024,3,3)
  const float* b_r  = (const float*)d_in[4];   // (256)
  const float* w2   = (const float*)d_in[5];   // (256,512,3,3)
  const float* b2   = (const float*)d_in[6];   // (256)
  const float* w3   = (const float*)d_in[7];   // (81,256,1,1)
  const float* b3   = (const float*)d_in[8];   // (81)
  float* out = (float*)d_out;                  // (4,1024,64,64)

  // workspace layout (fp32): cat(4,512,64,64) | x2(4,256,64,64) | kern(4,81,64,64)
  float* cat  = (float*)d_ws;
  float* x2   = cat + (size_t)4 * 512 * HW2;
  float* kern = x2 + (size_t)4 * 256 * HW2;

  // conv_reduce on current -> cat[:, 0:256], on key -> cat[:, 256:512]
  conv3x3_relu_k<<<dim3(16, 8, 4), 256, 0, stream>>>(cur,  w_r, b_r, cat, 1024, 0,   512);
  conv3x3_relu_k<<<dim3(16, 8, 4), 256, 0, stream>>>(keyl, w_r, b_r, cat, 1024, 256, 512);
  // conv2 on concat (512 -> 256)
  conv3x3_relu_k<<<dim3(16, 8, 4), 256, 0, stream>>>(cat,  w2,  b2,  x2,  512,  0,   256);
  // 1x1 head + softmax -> per-pixel 81 kernels
  head_softmax_k<<<dim3(256), 256, 0, stream>>>(x2, w3, b3, kern);
  // spatially-variant convolution
  svc_k<<<dim3(64, 64, 4), 256, 0, stream>>>(keyh, kern, out);
}

// Round 2
// 708.415 us; speedup vs baseline: 7.2961x; 7.2961x over previous
//
#include <hip/hip_runtime.h>
#include <math.h>

#define HW2 4096

typedef __attribute__((ext_vector_type(8))) short s16x8;
typedef __attribute__((ext_vector_type(4))) short s16x4;
typedef __attribute__((ext_vector_type(4))) float f32x4;

__device__ __forceinline__ unsigned short f2bf(float x) {
  unsigned int u = __float_as_uint(x);
  u += 0x7fff + ((u >> 16) & 1);          // RNE
  return (unsigned short)(u >> 16);
}

__device__ __forceinline__ void async16(void* lds, const void* g) {
  __builtin_amdgcn_global_load_lds(
      (const __attribute__((address_space(1))) void*)g,
      (__attribute__((address_space(3))) void*)lds, 16, 0, 0);
}

// ---------------------------------------------------------------------------
// Weight prep: fp32 OIHW (Cout,Cin,3,3) -> bf16 in MFMA A-frag order.
// Chunk (cob, cc) = 9216 shorts: [t 9][mt 2][q 4][ln 16][j 8]
//   element = W[co=cob*32+mt*16+ln][ci=cc*32+q*8+j][tap t]
// ---------------------------------------------------------------------------
__global__ __launch_bounds__(256) void wprep_k(const float* __restrict__ w,
                                               unsigned short* __restrict__ Wb,
                                               int Cin) {
  const int CC = Cin >> 5;
  int e = blockIdx.x * 256 + threadIdx.x;
  int ln = e & 15, q = (e >> 4) & 3, mt = (e >> 6) & 1;
  int rest = e >> 7;            // t + 9*(cc + CC*cob)
  int t = rest % 9;
  int g = rest / 9;
  int cc = g % CC, cob = g / CC;
  int co = cob * 32 + mt * 16 + ln;
  const float* src = w + ((size_t)co * Cin + cc * 32 + q * 8) * 9 + t;
  s16x8 v;
  #pragma unroll
  for (int j = 0; j < 8; ++j) v[j] = (short)f2bf(src[j * 9]);
  size_t dst = (size_t)(cob * CC + cc) * 9216 +
               ((size_t)((t * 2 + mt) * 4 + q) * 16 + ln) * 8;
  *(s16x8*)&Wb[dst] = v;
}

// ---------------------------------------------------------------------------
// 3x3 conv + bias + relu via MFMA bf16 implicit GEMM.
// Block: 32 co x (4 rows x 64 w) pixels. 4 waves; wave = 32co x (4r x 16w).
// K-loop over cin chunks of 32; 9 taps as shifted B-frags.
// LDS: sIn[6 rows][66 cols][32 ci] bf16 (halo=1), sW = frag-ordered chunk.
// SRC_BF16: input is transposed bf16 [b][h][cc][w*32+ci] (async load)
//           else fp32 NCHW (load+convert+transpose in staging).
// EPI_BF16: output transposed bf16 (chunk offset occ0, outCC chunks)
//           else fp32 NCHW (outCC = Cout).
// ---------------------------------------------------------------------------
template <int SRC_BF16, int EPI_BF16>
__global__ __launch_bounds__(256, 2) void conv_mfma_k(
    const void* __restrict__ inp,
    const unsigned short* __restrict__ Wb,
    const float* __restrict__ bias,
    void* __restrict__ outp,
    int CC, int occ0, int outCC)
{
  __shared__ short sIn[6 * 66 * 32];   // 25344 B
  __shared__ short sW[9216];           // 18432 B

  const int tid = threadIdx.x;
  const int lane = tid & 63;
  const int wid = tid >> 6;
  const int ln = lane & 15;
  const int q = lane >> 4;
  const int w0 = wid * 16;
  const int pb = blockIdx.x;
  const int b = pb >> 4;
  const int h0 = (pb & 15) * 4;
  const int cob = blockIdx.y;

  // zero halo cols (col 0 and 65) once
  if (tid < 48) {
    int r = tid >> 3, side = (tid >> 2) & 1, qq = tid & 3;
    int col = side ? 65 : 0;
    s16x8 z = (s16x8)0;
    *(s16x8*)&sIn[(r * 66 + col) * 32 + qq * 8] = z;
  }
  if (SRC_BF16) {
    // zero OOB rows once (they are never overwritten)
    for (int r = 0; r < 6; ++r) {
      int h = h0 - 1 + r;
      if (h < 0 || h > 63) {
        if (tid < 128) {
          s16x8 z = (s16x8)0;
          *(s16x8*)&sIn[(r * 66 + 1) * 32 + tid * 8] = z;
        }
      }
    }
  }

  f32x4 acc[2][4];
  #pragma unroll
  for (int mt = 0; mt < 2; ++mt)
    #pragma unroll
    for (int r = 0; r < 4; ++r) acc[mt][r] = (f32x4){0.f, 0.f, 0.f, 0.f};

  for (int cc = 0; cc < CC; ++cc) {
    // ---- stage weights (contiguous async 1KB segments per wave) ----
    {
      const unsigned short* gw = Wb + (size_t)(cob * CC + cc) * 9216;
      for (int s = wid; s < 18; s += 4)
        async16(&sW[s * 512 + lane * 8], gw + s * 512 + lane * 8);
    }
    // ---- stage input tile ----
    if (SRC_BF16) {
      const unsigned short* cat = (const unsigned short*)inp;
      #pragma unroll
      for (int k = 0; k < 6; ++k) {
        int h = h0 - 1 + k;
        if (h >= 0 && h <= 63) {
          const unsigned short* gsrc =
              cat + ((size_t)(b * 64 + h) * CC + cc) * 2048 + wid * 512 + lane * 8;
          async16(&sIn[(k * 66 + 1) * 32 + wid * 512 + lane * 8], gsrc);
        }
      }
    } else {
      const float* fin = (const float*)inp;
      const int sq = tid & 3, sw = tid >> 2;   // ci-octet, w
      #pragma unroll
      for (int r = 0; r < 6; ++r) {
        int h = h0 - 1 + r;
        s16x8 v;
        if (h >= 0 && h <= 63) {
          #pragma unroll
          for (int k = 0; k < 8; ++k) {
            float val = fin[((size_t)(b * (CC * 32) + cc * 32 + sq * 8 + k) << 12) +
                            h * 64 + sw];
            v[k] = (short)f2bf(val);
          }
        } else {
          v = (s16x8)0;
        }
        *(s16x8*)&sIn[(r * 66 + sw + 1) * 32 + sq * 8] = v;
      }
    }
    __syncthreads();
    // ---- compute: 9 taps x 2 m-tiles x 4 row-tiles ----
    #pragma unroll
    for (int kw = 0; kw < 3; ++kw) {
      s16x8 Bfr[6];
      #pragma unroll
      for (int rp = 0; rp < 6; ++rp)
        Bfr[rp] = *(const s16x8*)&sIn[(rp * 66 + w0 + kw + ln) * 32 + q * 8];
      #pragma unroll
      for (int kh = 0; kh < 3; ++kh) {
        #pragma unroll
        for (int mt = 0; mt < 2; ++mt) {
          s16x8 Afr = *(const s16x8*)&sW[((kh * 3 + kw) * 2 + mt) * 512 + lane * 8];
          #pragma unroll
          for (int r = 0; r < 4; ++r)
            acc[mt][r] = __builtin_amdgcn_mfma_f32_16x16x32_bf16(
                Afr, Bfr[r + kh], acc[mt][r], 0, 0, 0);
        }
      }
    }
    __syncthreads();
  }

  // ---- epilogue: bias + relu ----
  #pragma unroll
  for (int mt = 0; mt < 2; ++mt) {
    const float4 bv = *(const float4*)&bias[cob * 32 + mt * 16 + q * 4];
    #pragma unroll
    for (int r = 0; r < 4; ++r) {
      float y0 = fmaxf(acc[mt][r].x + bv.x, 0.f);
      float y1 = fmaxf(acc[mt][r].y + bv.y, 0.f);
      float y2 = fmaxf(acc[mt][r].z + bv.z, 0.f);
      float y3 = fmaxf(acc[mt][r].w + bv.w, 0.f);
      if (EPI_BF16) {
        s16x4 pk;
        pk[0] = (short)f2bf(y0); pk[1] = (short)f2bf(y1);
        pk[2] = (short)f2bf(y2); pk[3] = (short)f2bf(y3);
        unsigned short* ob = (unsigned short*)outp;
        size_t off = ((size_t)(b * 64 + h0 + r) * outCC + (occ0 + cob)) * 2048 +
                     (w0 + ln) * 32 + mt * 16 + q * 4;
        *(s16x4*)&ob[off] = pk;
      } else {
        float* ob = (float*)outp;
        int co = cob * 32 + mt * 16 + q * 4;
        size_t base = ((size_t)b * outCC + co) * HW2 + (h0 + r) * 64 + w0 + ln;
        ob[base] = y0;
        ob[base + HW2] = y1;
        ob[base + 2 * HW2] = y2;
        ob[base + 3 * HW2] = y3;
      }
    }
  }
}

// ---------------------------------------------------------------------------
// 1x1 head (256->81) + bias + relu + softmax.  Block = (b,h) row.
// Register accumulators: thread (w, cg) computes co = cg+4k, k<21.
// Each x2 value is loaded once per thread; w3 reads are wave-uniform (scalar).
// ---------------------------------------------------------------------------
__global__ __launch_bounds__(256) void head_k(
    const float* __restrict__ x2, const float* __restrict__ w3,
    const float* __restrict__ b3, float* __restrict__ kern)
{
  __shared__ float sS[81 * 64];
  const int bh = blockIdx.x;
  const int b = bh >> 6, h = bh & 63;
  const int tid = threadIdx.x;
  const int w = tid & 63, cg = tid >> 6;

  float s[21];
  #pragma unroll
  for (int k = 0; k < 21; ++k) {
    int co = cg + 4 * k;
    s[k] = (co < 81) ? b3[co] : 0.f;
  }

  const float* xp = x2 + (size_t)b * 256 * HW2 + h * 64 + w;
  for (int c0 = 0; c0 < 256; c0 += 8) {
    float xv[8];
    #pragma unroll
    for (int j = 0; j < 8; ++j) xv[j] = xp[(size_t)(c0 + j) * HW2];
    #pragma unroll
    for (int k = 0; k < 21; ++k) {
      int co = cg + 4 * k;
      if (co < 81) {
        const float* wp = w3 + co * 256 + c0;
        #pragma unroll
        for (int j = 0; j < 8; ++j) s[k] += xv[j] * wp[j];
      }
    }
  }
  #pragma unroll
  for (int k = 0; k < 21; ++k) {
    int co = cg + 4 * k;
    if (co < 81) sS[co * 64 + w] = fmaxf(s[k], 0.f);
  }
  __syncthreads();
  if (tid < 64) {
    float m = -1e30f;
    for (int c = 0; c < 81; ++c) m = fmaxf(m, sS[c * 64 + tid]);
    float sum = 0.f;
    for (int c = 0; c < 81; ++c) {
      float e = __expf(sS[c * 64 + tid] - m);
      sS[c * 64 + tid] = e;
      sum += e;
    }
    float rr = 1.f / sum;
    for (int c = 0; c < 81; ++c)
      kern[((size_t)(b * 81 + c)) * HW2 + h * 64 + tid] = sS[c * 64 + tid] * rr;
  }
}

// ---------------------------------------------------------------------------
// Spatially-variant conv. Block = (b, h, 64-channel chunk), 256 threads:
// (wq 16) x (cs 16); each thread: 4 channels x 4 w. kern row staged in LDS
// once per (b,h,cblk); feats straight from global (L2 absorbs halo overlap).
// ---------------------------------------------------------------------------
__global__ __launch_bounds__(256) void svc_k2(
    const float* __restrict__ feats, const float* __restrict__ kern,
    float* __restrict__ out)
{
  __shared__ float sK[81 * 64];
  const int b = blockIdx.z, h = blockIdx.y, cb = blockIdx.x * 64;
  const int tid = threadIdx.x;
  for (int e = tid; e < 81 * 64; e += 256)
    sK[e] = kern[((size_t)(b * 81) + (e >> 6)) * HW2 + h * 64 + (e & 63)];
  __syncthreads();

  const int wq = tid & 15, cs = tid >> 4;
  const int w0 = wq * 4;
  float4 acc[4];
  #pragma unroll
  for (int ch = 0; ch < 4; ++ch) acc[ch] = make_float4(0.f, 0.f, 0.f, 0.f);

  for (int i = 0; i < 9; ++i) {
    int hh = h + i - 4;
    if (hh < 0 || hh > 63) continue;
    float f[4][12];
    #pragma unroll
    for (int ch = 0; ch < 4; ++ch) {
      const float* fp = feats + ((size_t)(b * 1024 + cb + cs * 4 + ch)) * HW2 + hh * 64;
      float4 L = (wq == 0) ? make_float4(0.f, 0.f, 0.f, 0.f)
                           : *(const float4*)(fp + w0 - 4);
      float4 M = *(const float4*)(fp + w0);
      float4 R = (wq == 15) ? make_float4(0.f, 0.f, 0.f, 0.f)
                            : *(const float4*)(fp + w0 + 4);
      f[ch][0] = L.x; f[ch][1] = L.y; f[ch][2]  = L.z; f[ch][3]  = L.w;
      f[ch][4] = M.x; f[ch][5] = M.y; f[ch][6]  = M.z; f[ch][7]  = M.w;
      f[ch][8] = R.x; f[ch][9] = R.y; f[ch][10] = R.z; f[ch][11] = R.w;
    }
    #pragma unroll
    for (int j = 0; j < 9; ++j) {
      const float4 kv = *(const float4*)&sK[(i * 9 + j) * 64 + w0];
      #pragma unroll
      for (int ch = 0; ch < 4; ++ch) {
        acc[ch].x += f[ch][j]     * kv.x;
        acc[ch].y += f[ch][j + 1] * kv.y;
        acc[ch].z += f[ch][j + 2] * kv.z;
        acc[ch].w += f[ch][j + 3] * kv.w;
      }
    }
  }
  #pragma unroll
  for (int ch = 0; ch < 4; ++ch)
    *(float4*)&out[((size_t)(b * 1024 + cb + cs * 4 + ch)) * HW2 + h * 64 + w0] =
        acc[ch];
}

// ---------------------------------------------------------------------------
extern "C" void kernel_launch(void* const* d_in, const int* in_sizes, int n_in,
                              void* d_out, int out_size, void* d_ws, size_t ws_size,
                              hipStream_t stream) {
  const float* cur  = (const float*)d_in[0];
  const float* keyl = (const float*)d_in[1];
  const float* keyh = (const float*)d_in[2];
  const float* w_r  = (const float*)d_in[3];
  const float* b_r  = (const float*)d_in[4];
  const float* w2   = (const float*)d_in[5];
  const float* b2   = (const float*)d_in[6];
  const float* w3   = (const float*)d_in[7];
  const float* b3   = (const float*)d_in[8];
  float* out = (float*)d_out;

  // workspace: cat bf16-T (16.78MB) | x2 fp32 (16.78MB) | kern (5.31MB)
  //            | Wb1 bf16 (4.72MB) | Wb2 bf16 (2.36MB)  — total 45.94MB
  char* ws = (char*)d_ws;
  unsigned short* cat  = (unsigned short*)ws;
  float*          x2   = (float*)(ws + 16777216);
  float*          kern = (float*)(ws + 33554432);
  unsigned short* Wb1  = (unsigned short*)(ws + 38862848);
  unsigned short* Wb2  = (unsigned short*)(ws + 43581440);

  wprep_k<<<1152, 256, 0, stream>>>(w_r, Wb1, 1024);
  wprep_k<<<576,  256, 0, stream>>>(w2,  Wb2, 512);

  // conv_reduce (1024->256) on cur -> cat chunks 0..7, keyl -> chunks 8..15
  conv_mfma_k<0, 1><<<dim3(64, 8), 256, 0, stream>>>(cur,  Wb1, b_r, cat, 32, 0, 16);
  conv_mfma_k<0, 1><<<dim3(64, 8), 256, 0, stream>>>(keyl, Wb1, b_r, cat, 32, 8, 16);
  // conv2 (512->256), reads bf16-T cat, writes fp32 NCHW x2
  conv_mfma_k<1, 0><<<dim3(64, 8), 256, 0, stream>>>(cat,  Wb2, b2, x2, 16, 0, 256);

  head_k<<<256, 256, 0, stream>>>(x2, w3, b3, kern);
  svc_k2<<<dim3(16, 64, 4), 256, 0, stream>>>(keyh, kern, out);
}

// Round 3
// 598.481 us; speedup vs baseline: 8.6363x; 1.1837x over previous
//
#include <hip/hip_runtime.h>
#include <math.h>

#define HW2 4096

typedef __attribute__((ext_vector_type(8))) short s16x8;
typedef __attribute__((ext_vector_type(4))) short s16x4;
typedef __attribute__((ext_vector_type(4))) float f32x4;

__device__ __forceinline__ unsigned short f2bf(float x) {
  unsigned int u = __float_as_uint(x);
  u += 0x7fff + ((u >> 16) & 1);          // RNE
  return (unsigned short)(u >> 16);
}

__device__ __forceinline__ void async16(void* lds, const void* g) {
  __builtin_amdgcn_global_load_lds(
      (const __attribute__((address_space(1))) void*)g,
      (__attribute__((address_space(3))) void*)lds, 16, 0, 0);
}

// ---------------------------------------------------------------------------
// fp32 NCHW -> bf16 transposed [b][h][cc][w*32+ci].  Block = (cc, h8, b).
// Coalesced float4 reads, LDS transpose (ci-stride 534 shorts -> the 8-short
// gather hits 32 distinct banks), 1KB-contiguous s16x8 writes.
// ---------------------------------------------------------------------------
__global__ __launch_bounds__(256) void tpose_k(
    const float* __restrict__ in, unsigned short* __restrict__ outT, int CC)
{
  __shared__ short sT[32 * 534];
  const int cc = blockIdx.x;
  const int h0 = blockIdx.y * 8;
  const int b  = blockIdx.z;
  const int tid = threadIdx.x;
  const float* ip = in + (size_t)(b * CC + cc) * 32 * 4096;

  for (int e = tid; e < 4096; e += 256) {
    int ci = e >> 7, rem = e & 127;
    int h = rem >> 4, w4 = rem & 15;
    float4 v = *(const float4*)&ip[(size_t)ci * 4096 + (h0 + h) * 64 + w4 * 4];
    short* d = &sT[ci * 534 + h * 66 + w4 * 4];
    d[0] = (short)f2bf(v.x); d[1] = (short)f2bf(v.y);
    d[2] = (short)f2bf(v.z); d[3] = (short)f2bf(v.w);
  }
  __syncthreads();
  unsigned short* ob = outT + (size_t)b * 64 * CC * 2048;
  for (int e = tid; e < 2048; e += 256) {
    int h = e >> 8, rem = e & 255;
    int w = rem >> 2, q = rem & 3;
    s16x8 v;
    #pragma unroll
    for (int j = 0; j < 8; ++j) v[j] = sT[(q * 8 + j) * 534 + h * 66 + w];
    *(s16x8*)&ob[((size_t)(h0 + h) * CC + cc) * 2048 + w * 32 + q * 8] = v;
  }
}

// ---------------------------------------------------------------------------
// Weight prep (coalesced): fp32 OIHW -> bf16 MFMA A-frag order.
// Block per (cob, cc) chunk: stage 32x288 floats via float4 (contiguous per
// co row), then gather-write s16x8 in frag order [t][mt][q][ln][j].
// ---------------------------------------------------------------------------
__global__ __launch_bounds__(256) void wprep_k(const float* __restrict__ w,
                                               unsigned short* __restrict__ Wb,
                                               int Cin) {
  __shared__ float sC[32 * 289];
  const int CC = Cin >> 5;
  const int cc = blockIdx.x % CC, cob = blockIdx.x / CC;
  const int tid = threadIdx.x;
  for (int e = tid; e < 2304; e += 256) {
    int co = e / 72, off = e % 72;
    float4 v = *(const float4*)&w[((size_t)(cob * 32 + co) * Cin + cc * 32) * 9 +
                                  off * 4];
    float* d = &sC[co * 289 + off * 4];
    d[0] = v.x; d[1] = v.y; d[2] = v.z; d[3] = v.w;
  }
  __syncthreads();
  unsigned short* ob = Wb + (size_t)(cob * CC + cc) * 9216;
  for (int e = tid; e < 1152; e += 256) {
    int ln = e & 15, q = (e >> 4) & 3, mt = (e >> 6) & 1, t = e >> 7;
    s16x8 v;
    #pragma unroll
    for (int j = 0; j < 8; ++j)
      v[j] = (short)f2bf(sC[(mt * 16 + ln) * 289 + (q * 8 + j) * 9 + t]);
    *(s16x8*)&ob[(size_t)e * 8] = v;
  }
}

// ---------------------------------------------------------------------------
// 3x3 conv + bias + relu via MFMA bf16 implicit GEMM.
// Block: 32 co x (4 rows x 64 w). SRC_BF16=1: async global_load_lds from the
// transposed bf16 layout. SRC_BF16=0 (fallback): fp32 NCHW convert-stage.
// ---------------------------------------------------------------------------
template <int SRC_BF16, int EPI_BF16>
__global__ __launch_bounds__(256, 3) void conv_mfma_k(
    const void* __restrict__ inp,
    const unsigned short* __restrict__ Wb,
    const float* __restrict__ bias,
    void* __restrict__ outp,
    int CC, int occ0, int outCC)
{
  __shared__ short sIn[6 * 66 * 32];   // 25344 B
  __shared__ short sW[9216];           // 18432 B

  const int tid = threadIdx.x;
  const int lane = tid & 63;
  const int wid = tid >> 6;
  const int ln = lane & 15;
  const int q = lane >> 4;
  const int w0 = wid * 16;
  const int pb = blockIdx.x;
  const int b = pb >> 4;
  const int h0 = (pb & 15) * 4;
  const int cob = blockIdx.y;

  // zero halo cols (col 0 and 65) once
  if (tid < 48) {
    int r = tid >> 3, side = (tid >> 2) & 1, qq = tid & 3;
    int col = side ? 65 : 0;
    s16x8 z = (s16x8)0;
    *(s16x8*)&sIn[(r * 66 + col) * 32 + qq * 8] = z;
  }
  if (SRC_BF16) {
    // zero OOB rows once (never async-overwritten): full 2048 shorts per row
    #pragma unroll
    for (int r = 0; r < 6; ++r) {
      int h = h0 - 1 + r;
      if (h < 0 || h > 63) {
        s16x8 z = (s16x8)0;
        *(s16x8*)&sIn[(r * 66 + 1) * 32 + tid * 8] = z;
      }
    }
  }

  f32x4 acc[2][4];
  #pragma unroll
  for (int mt = 0; mt < 2; ++mt)
    #pragma unroll
    for (int r = 0; r < 4; ++r) acc[mt][r] = (f32x4){0.f, 0.f, 0.f, 0.f};

  for (int cc = 0; cc < CC; ++cc) {
    // ---- stage weights ----
    {
      const unsigned short* gw = Wb + (size_t)(cob * CC + cc) * 9216;
      for (int s = wid; s < 18; s += 4)
        async16(&sW[s * 512 + lane * 8], gw + s * 512 + lane * 8);
    }
    // ---- stage input tile ----
    if (SRC_BF16) {
      const unsigned short* cat = (const unsigned short*)inp;
      #pragma unroll
      for (int k = 0; k < 6; ++k) {
        int h = h0 - 1 + k;
        if (h >= 0 && h <= 63) {
          const unsigned short* gsrc =
              cat + ((size_t)(b * 64 + h) * CC + cc) * 2048 + wid * 512 + lane * 8;
          async16(&sIn[(k * 66 + 1) * 32 + wid * 512 + lane * 8], gsrc);
        }
      }
    } else {
      const float* fin = (const float*)inp;
      const int sq = tid & 3, sw = tid >> 2;
      #pragma unroll
      for (int r = 0; r < 6; ++r) {
        int h = h0 - 1 + r;
        s16x8 v;
        if (h >= 0 && h <= 63) {
          #pragma unroll
          for (int k = 0; k < 8; ++k) {
            float val = fin[((size_t)(b * (CC * 32) + cc * 32 + sq * 8 + k) << 12) +
                            h * 64 + sw];
            v[k] = (short)f2bf(val);
          }
        } else {
          v = (s16x8)0;
        }
        *(s16x8*)&sIn[(r * 66 + sw + 1) * 32 + sq * 8] = v;
      }
    }
    __syncthreads();
    // ---- compute: 9 taps x 2 m-tiles x 4 row-tiles ----
    #pragma unroll
    for (int kw = 0; kw < 3; ++kw) {
      s16x8 Bfr[6];
      #pragma unroll
      for (int rp = 0; rp < 6; ++rp)
        Bfr[rp] = *(const s16x8*)&sIn[(rp * 66 + w0 + kw + ln) * 32 + q * 8];
      #pragma unroll
      for (int kh = 0; kh < 3; ++kh) {
        #pragma unroll
        for (int mt = 0; mt < 2; ++mt) {
          s16x8 Afr = *(const s16x8*)&sW[((kh * 3 + kw) * 2 + mt) * 512 + lane * 8];
          #pragma unroll
          for (int r = 0; r < 4; ++r)
            acc[mt][r] = __builtin_amdgcn_mfma_f32_16x16x32_bf16(
                Afr, Bfr[r + kh], acc[mt][r], 0, 0, 0);
        }
      }
    }
    __syncthreads();
  }

  // ---- epilogue: bias + relu ----
  #pragma unroll
  for (int mt = 0; mt < 2; ++mt) {
    const float4 bv = *(const float4*)&bias[cob * 32 + mt * 16 + q * 4];
    #pragma unroll
    for (int r = 0; r < 4; ++r) {
      float y0 = fmaxf(acc[mt][r].x + bv.x, 0.f);
      float y1 = fmaxf(acc[mt][r].y + bv.y, 0.f);
      float y2 = fmaxf(acc[mt][r].z + bv.z, 0.f);
      float y3 = fmaxf(acc[mt][r].w + bv.w, 0.f);
      if (EPI_BF16) {
        s16x4 pk;
        pk[0] = (short)f2bf(y0); pk[1] = (short)f2bf(y1);
        pk[2] = (short)f2bf(y2); pk[3] = (short)f2bf(y3);
        unsigned short* ob = (unsigned short*)outp;
        size_t off = ((size_t)(b * 64 + h0 + r) * outCC + (occ0 + cob)) * 2048 +
                     (w0 + ln) * 32 + mt * 16 + q * 4;
        *(s16x4*)&ob[off] = pk;
      } else {
        float* ob = (float*)outp;
        int co = cob * 32 + mt * 16 + q * 4;
        size_t base = ((size_t)b * outCC + co) * HW2 + (h0 + r) * 64 + w0 + ln;
        ob[base] = y0;
        ob[base + HW2] = y1;
        ob[base + 2 * HW2] = y2;
        ob[base + 3 * HW2] = y3;
      }
    }
  }
}

// ---------------------------------------------------------------------------
// 1x1 head (256->81) + bias + relu + softmax.  Block = (b,h) row.
// ---------------------------------------------------------------------------
__global__ __launch_bounds__(256) void head_k(
    const float* __restrict__ x2, const float* __restrict__ w3,
    const float* __restrict__ b3, float* __restrict__ kern)
{
  __shared__ float sS[81 * 64];
  const int bh = blockIdx.x;
  const int b = bh >> 6, h = bh & 63;
  const int tid = threadIdx.x;
  const int w = tid & 63, cg = tid >> 6;

  float s[21];
  #pragma unroll
  for (int k = 0; k < 21; ++k) {
    int co = cg + 4 * k;
    s[k] = (co < 81) ? b3[co] : 0.f;
  }

  const float* xp = x2 + (size_t)b * 256 * HW2 + h * 64 + w;
  for (int c0 = 0; c0 < 256; c0 += 8) {
    float xv[8];
    #pragma unroll
    for (int j = 0; j < 8; ++j) xv[j] = xp[(size_t)(c0 + j) * HW2];
    #pragma unroll
    for (int k = 0; k < 21; ++k) {
      int co = cg + 4 * k;
      if (co < 81) {
        const float* wp = w3 + co * 256 + c0;
        #pragma unroll
        for (int j = 0; j < 8; ++j) s[k] += xv[j] * wp[j];
      }
    }
  }
  #pragma unroll
  for (int k = 0; k < 21; ++k) {
    int co = cg + 4 * k;
    if (co < 81) sS[co * 64 + w] = fmaxf(s[k], 0.f);
  }
  __syncthreads();
  if (tid < 64) {
    float m = -1e30f;
    for (int c = 0; c < 81; ++c) m = fmaxf(m, sS[c * 64 + tid]);
    float sum = 0.f;
    for (int c = 0; c < 81; ++c) {
      float e = __expf(sS[c * 64 + tid] - m);
      sS[c * 64 + tid] = e;
      sum += e;
    }
    float rr = 1.f / sum;
    for (int c = 0; c < 81; ++c)
      kern[((size_t)(b * 81 + c)) * HW2 + h * 64 + tid] = sS[c * 64 + tid] * rr;
  }
}

// ---------------------------------------------------------------------------
// Spatially-variant conv. Block = (b, h, 64-ch chunk); kern row in LDS.
// ---------------------------------------------------------------------------
__global__ __launch_bounds__(256) void svc_k2(
    const float* __restrict__ feats, const float* __restrict__ kern,
    float* __restrict__ out)
{
  __shared__ float sK[81 * 64];
  const int b = blockIdx.z, h = blockIdx.y, cb = blockIdx.x * 64;
  const int tid = threadIdx.x;
  for (int e = tid; e < 81 * 64; e += 256)
    sK[e] = kern[((size_t)(b * 81) + (e >> 6)) * HW2 + h * 64 + (e & 63)];
  __syncthreads();

  const int wq = tid & 15, cs = tid >> 4;
  const int w0 = wq * 4;
  float4 acc[4];
  #pragma unroll
  for (int ch = 0; ch < 4; ++ch) acc[ch] = make_float4(0.f, 0.f, 0.f, 0.f);

  for (int i = 0; i < 9; ++i) {
    int hh = h + i - 4;
    if (hh < 0 || hh > 63) continue;
    float f[4][12];
    #pragma unroll
    for (int ch = 0; ch < 4; ++ch) {
      const float* fp = feats + ((size_t)(b * 1024 + cb + cs * 4 + ch)) * HW2 + hh * 64;
      float4 L = (wq == 0) ? make_float4(0.f, 0.f, 0.f, 0.f)
                           : *(const float4*)(fp + w0 - 4);
      float4 M = *(const float4*)(fp + w0);
      float4 R = (wq == 15) ? make_float4(0.f, 0.f, 0.f, 0.f)
                            : *(const float4*)(fp + w0 + 4);
      f[ch][0] = L.x; f[ch][1] = L.y; f[ch][2]  = L.z; f[ch][3]  = L.w;
      f[ch][4] = M.x; f[ch][5] = M.y; f[ch][6]  = M.z; f[ch][7]  = M.w;
      f[ch][8] = R.x; f[ch][9] = R.y; f[ch][10] = R.z; f[ch][11] = R.w;
    }
    #pragma unroll
    for (int j = 0; j < 9; ++j) {
      const float4 kv = *(const float4*)&sK[(i * 9 + j) * 64 + w0];
      #pragma unroll
      for (int ch = 0; ch < 4; ++ch) {
        acc[ch].x += f[ch][j]     * kv.x;
        acc[ch].y += f[ch][j + 1] * kv.y;
        acc[ch].z += f[ch][j + 2] * kv.z;
        acc[ch].w += f[ch][j + 3] * kv.w;
      }
    }
  }
  #pragma unroll
  for (int ch = 0; ch < 4; ++ch)
    *(float4*)&out[((size_t)(b * 1024 + cb + cs * 4 + ch)) * HW2 + h * 64 + w0] =
        acc[ch];
}

// ---------------------------------------------------------------------------
extern "C" void kernel_launch(void* const* d_in, const int* in_sizes, int n_in,
                              void* d_out, int out_size, void* d_ws, size_t ws_size,
                              hipStream_t stream) {
  const float* cur  = (const float*)d_in[0];
  const float* keyl = (const float*)d_in[1];
  const float* keyh = (const float*)d_in[2];
  const float* w_r  = (const float*)d_in[3];
  const float* b_r  = (const float*)d_in[4];
  const float* w2   = (const float*)d_in[5];
  const float* b2   = (const float*)d_in[6];
  const float* w3   = (const float*)d_in[7];
  const float* b3   = (const float*)d_in[8];
  float* out = (float*)d_out;
  char* ws = (char*)d_ws;

  const size_t NEED_FAST = 57409536;
  if (ws_size >= NEED_FAST) {
    // fast path layout:
    //   cat bf16-T 16.78MB | Wb1 4.72MB | Wb2 2.36MB | region0 33.55MB
    //   region0: bufA (bf16-T input, reused cur->keyl) then {x2, kern} overlay
    unsigned short* cat  = (unsigned short*)ws;
    unsigned short* Wb1  = (unsigned short*)(ws + 16777216);
    unsigned short* Wb2  = (unsigned short*)(ws + 21495808);
    unsigned short* bufA = (unsigned short*)(ws + 23855104);
    float*          x2   = (float*)(ws + 23855104);
    float*          kern = (float*)(ws + 40632320);

    wprep_k<<<256, 256, 0, stream>>>(w_r, Wb1, 1024);
    wprep_k<<<128, 256, 0, stream>>>(w2,  Wb2, 512);

    tpose_k<<<dim3(32, 8, 4), 256, 0, stream>>>(cur, bufA, 32);
    conv_mfma_k<1, 1><<<dim3(64, 8), 256, 0, stream>>>(bufA, Wb1, b_r, cat, 32, 0, 16);
    tpose_k<<<dim3(32, 8, 4), 256, 0, stream>>>(keyl, bufA, 32);
    conv_mfma_k<1, 1><<<dim3(64, 8), 256, 0, stream>>>(bufA, Wb1, b_r, cat, 32, 8, 16);
    conv_mfma_k<1, 0><<<dim3(64, 8), 256, 0, stream>>>(cat, Wb2, b2, x2, 16, 0, 256);

    head_k<<<256, 256, 0, stream>>>(x2, w3, b3, kern);
    svc_k2<<<dim3(16, 64, 4), 256, 0, stream>>>(keyh, kern, out);
  } else {
    // fallback (round-2 flow, 45.94MB)
    unsigned short* cat  = (unsigned short*)ws;
    float*          x2   = (float*)(ws + 16777216);
    float*          kern = (float*)(ws + 33554432);
    unsigned short* Wb1  = (unsigned short*)(ws + 38862848);
    unsigned short* Wb2  = (unsigned short*)(ws + 43581440);

    wprep_k<<<256, 256, 0, stream>>>(w_r, Wb1, 1024);
    wprep_k<<<128, 256, 0, stream>>>(w2,  Wb2, 512);

    conv_mfma_k<0, 1><<<dim3(64, 8), 256, 0, stream>>>(cur,  Wb1, b_r, cat, 32, 0, 16);
    conv_mfma_k<0, 1><<<dim3(64, 8), 256, 0, stream>>>(keyl, Wb1, b_r, cat, 32, 8, 16);
    conv_mfma_k<1, 0><<<dim3(64, 8), 256, 0, stream>>>(cat,  Wb2, b2, x2, 16, 0, 256);

    head_k<<<256, 256, 0, stream>>>(x2, w3, b3, kern);
    svc_k2<<<dim3(16, 64, 4), 256, 0, stream>>>(keyh, kern, out);
  }
}